// Round 2
// baseline (82260.602 us; speedup 1.0000x reference)
//
#include <hip/hip_runtime.h>
#include <stdint.h>

// Problem constants (match reference)
#define B 128
#define S 256
#define T 256
#define EMBED 256
#define ENC 256
#define DEC 512
#define DOF 4

typedef __attribute__((ext_vector_type(8))) short bf16x8;   // 8 bf16 = 4 VGPRs (MFMA A/B frag)
typedef __attribute__((ext_vector_type(4))) float f32x4;    // MFMA C/D frag

static __device__ __forceinline__ float bf2f(unsigned short u){
  union{uint32_t u;float f;}c; c.u = ((uint32_t)u)<<16; return c.f;
}
static __device__ __forceinline__ unsigned short f2bf(float f){
  union{float f;uint32_t u;}c; c.f=f; uint32_t u=c.u;
  u += 0x7fffu + ((u>>16)&1u);  // round-to-nearest-even
  return (unsigned short)(u>>16);
}
static __device__ __forceinline__ void unp2(uint32_t w, float&a, float&b){
  union{uint32_t u;float f;}c1,c2; c1.u = w<<16; c2.u = w & 0xffff0000u; a=c1.f; b=c2.f;
}
static __device__ __forceinline__ float sigm(float x){ return 1.0f/(1.0f+__expf(-x)); }

// ---------------------------------------------------------------------------
// Device-scope monotonic barrier (grid co-resident by construction: 256 blocks
// of 256 thr, <40KB LDS -> >=3 blocks/CU capacity on 256 CUs).
// ---------------------------------------------------------------------------
static __device__ __forceinline__ void bar_arrive(unsigned* cnt){
  __threadfence();
  __syncthreads();
  if (threadIdx.x == 0)
    __hip_atomic_fetch_add(cnt, 1u, __ATOMIC_RELEASE, __HIP_MEMORY_SCOPE_AGENT);
}
static __device__ __forceinline__ void bar_wait(unsigned* cnt, unsigned target){
  if (threadIdx.x == 0){
    while (__hip_atomic_load(cnt, __ATOMIC_ACQUIRE, __HIP_MEMORY_SCOPE_AGENT) < target)
      __builtin_amdgcn_s_sleep(1);
  }
  __syncthreads();
  __threadfence();
}

// ---------------------------------------------------------------------------
// bf16 MFMA GEMM core for the (parallel) proj GEMM. 64x32 C tile.
// ---------------------------------------------------------------------------
static __device__ __forceinline__ void gemm_tile(
    const unsigned short* __restrict__ s0, int l0, int ld0,
    const unsigned short* __restrict__ s1, int l1, int ld1,
    const unsigned short* __restrict__ W, int ldw,
    int m_base, int n_base, char* smem, f32x4* acc)
{
  unsigned short* As = (unsigned short*)smem;     // 64 x 72
  unsigned short* Bs = As + 64*72;                // 32 x 72
  const int tid  = threadIdx.x;
  const int lane = tid & 63;
  const int wid  = tid >> 6;
  const int wm = wid >> 1, wn = wid & 1;
  const int l16 = lane & 15, qd = lane >> 4;
  const int Ktot = l0 + l1;
  const int ar = tid >> 2, aco = (tid & 3) * 16;
  const int br = (tid & 127) >> 2, bco = (tid & 3) * 16;
  const bool loadB = (tid >= 128);

  for (int ktb = 0; ktb < Ktot; ktb += 64){
    const unsigned short* ap; int ld, kloc;
    if (ktb < l0){ ap = s0; ld = ld0; kloc = ktb; }
    else         { ap = s1; ld = ld1; kloc = ktb - l0; }
    const unsigned short* arow = ap + (size_t)(m_base + ar) * ld + kloc + aco;
    uint4 av0 = *(const uint4*)(arow);
    uint4 av1 = *(const uint4*)(arow + 8);
    uint4 bv0, bv1;
    if (loadB){
      const unsigned short* brow = W + (size_t)(n_base + br) * ldw + ktb + bco;
      bv0 = *(const uint4*)(brow);
      bv1 = *(const uint4*)(brow + 8);
    }
    __syncthreads();
    *(uint4*)&As[ar*72 + aco]     = av0;
    *(uint4*)&As[ar*72 + aco + 8] = av1;
    if (loadB){
      *(uint4*)&Bs[br*72 + bco]     = bv0;
      *(uint4*)&Bs[br*72 + bco + 8] = bv1;
    }
    __syncthreads();
#pragma unroll
    for (int kh = 0; kh < 2; ++kh){
      const int ko = kh*32 + qd*8;
      bf16x8 a0 = *(bf16x8*)&As[(wm*32      + l16)*72 + ko];
      bf16x8 a1 = *(bf16x8*)&As[(wm*32 + 16 + l16)*72 + ko];
      bf16x8 bb = *(bf16x8*)&Bs[(wn*16      + l16)*72 + ko];
      acc[0] = __builtin_amdgcn_mfma_f32_16x16x32_bf16(a0, bb, acc[0], 0, 0, 0);
      acc[1] = __builtin_amdgcn_mfma_f32_16x16x32_bf16(a1, bb, acc[1], 0, 0, 0);
    }
  }
}

__global__ __launch_bounds__(256) void k_gemm_plain(
  const unsigned short* __restrict__ s0,int l0,int ld0,
  const unsigned short* __restrict__ s1,int l1,int ld1,
  const unsigned short* __restrict__ W,int ldw,int ntiles,
  unsigned short* Cbf, int ldc, int dotanh)
{
  __shared__ __align__(16) char smem[13824];
  const int bid = blockIdx.x;
  const int mt = bid / ntiles, nt = bid % ntiles;
  const int m_base = mt*64, n_base = nt*32;
  f32x4 acc[2];
  acc[0] = (f32x4){0.f,0.f,0.f,0.f};
  acc[1] = (f32x4){0.f,0.f,0.f,0.f};
  gemm_tile(s0,l0,ld0, s1,l1,ld1, W,ldw, m_base,n_base, smem, acc);
  const int tid = threadIdx.x, lane = tid & 63, wid = tid >> 6;
  const int wm = wid >> 1, wn = wid & 1, l16 = lane & 15, qd = lane >> 4;
#pragma unroll
  for (int tl = 0; tl < 2; ++tl)
#pragma unroll
    for (int r = 0; r < 4; ++r){
      float v = acc[tl][r];
      if (dotanh) v = tanhf(v);
      const int m = m_base + wm*32 + tl*16 + qd*4 + r;
      Cbf[(size_t)m*ldc + n_base + wn*16 + l16] = f2bf(v);
    }
}

// ---------------------------------------------------------------------------
// Persistent bi-LSTM encoder. Grid 256 = dir(2) x mg(2) x ng(64).
// Block: batches [mg*64,+64), gate cols [ng*16,+16) (units [ng*4,+4)).
// Weight slice (16x512) lives in LDS for all 256 steps; c lives in registers.
// Per-direction monotonic barrier each step.
// ---------------------------------------------------------------------------
__global__ __launch_bounds__(256,1) void k_encoder(
  const unsigned short* __restrict__ emb,   // (S,B,256)
  const unsigned short* __restrict__ WF, const unsigned short* __restrict__ WB,
  const float* __restrict__ bF, const float* __restrict__ bB,
  unsigned short* __restrict__ hEnc,        // [dir][2][B][256]
  unsigned short* __restrict__ encOut,      // [B][S][512]
  unsigned* __restrict__ cnt)               // +0: fwd, +32: bwd
{
  __shared__ __align__(16) unsigned short Ws[16*520];
  __shared__ __align__(16) float Gs[64*17];
  const int bid = blockIdx.x;
  const int dir = bid >> 7;
  const int mg  = (bid >> 6) & 1;
  const int ng  = bid & 63;
  const int tid = threadIdx.x;
  const int lane = tid & 63, w = tid >> 6;
  const int l16 = lane & 15, qd = lane >> 4;
  const int m_base = mg * 64;
  unsigned* mycnt = cnt + dir*32;

  const unsigned short* Wg = (dir ? WB : WF) + (size_t)ng*16*512;
  for (int i = tid; i < 16*64; i += 256){
    const int r = i >> 6, s = i & 63;
    *(uint4*)&Ws[r*520 + s*8] = *(const uint4*)&Wg[r*512 + s*8];
  }
  const float* bias = dir ? bB : bF;
  const int bl = tid & 63, u = tid >> 6;
  const float b0 = bias[ng*16 + u*4 + 0];
  const float b1 = bias[ng*16 + u*4 + 1];
  const float b2 = bias[ng*16 + u*4 + 2];
  const float b3 = bias[ng*16 + u*4 + 3];
  float c = 0.f;
  __syncthreads();

  for (int t = 0; t < S; ++t){
    if (t) bar_wait(mycnt, (unsigned)(128u*(unsigned)t));
    const int tt = dir ? (S-1-t) : t;
    const unsigned short* Ae = emb + ((size_t)tt*B + m_base + w*16 + l16)*256 + qd*8;
    const unsigned short* Ah = hEnc + (((size_t)dir*2 + (size_t)(t&1))*B + m_base + w*16 + l16)*256 + qd*8;
    f32x4 acc = (f32x4){0.f,0.f,0.f,0.f};
#pragma unroll 8
    for (int ks = 0; ks < 8; ++ks){
      bf16x8 a  = *(const bf16x8*)(Ae + ks*32);
      bf16x8 bb = *(const bf16x8*)&Ws[l16*520 + ks*32 + qd*8];
      acc = __builtin_amdgcn_mfma_f32_16x16x32_bf16(a, bb, acc, 0, 0, 0);
    }
#pragma unroll 8
    for (int ks = 0; ks < 8; ++ks){
      bf16x8 a  = *(const bf16x8*)(Ah + ks*32);
      bf16x8 bb = *(const bf16x8*)&Ws[l16*520 + 256 + ks*32 + qd*8];
      acc = __builtin_amdgcn_mfma_f32_16x16x32_bf16(a, bb, acc, 0, 0, 0);
    }
    __syncthreads();
#pragma unroll
    for (int r = 0; r < 4; ++r)
      Gs[(w*16 + qd*4 + r)*17 + l16] = acc[r];
    __syncthreads();
    const float gi = Gs[bl*17 + u*4 + 0] + b0;
    const float gf = Gs[bl*17 + u*4 + 1] + b1;
    const float gg = Gs[bl*17 + u*4 + 2] + b2;
    const float go = Gs[bl*17 + u*4 + 3] + b3;
    const float cn = sigm(gf)*c + sigm(gi)*tanhf(gg);
    c = cn;
    const unsigned short hb = f2bf(sigm(go)*tanhf(cn));
    const int bb2 = m_base + bl, j = ng*4 + u;
    hEnc[(((size_t)dir*2 + (size_t)((t+1)&1))*B + bb2)*256 + j] = hb;
    encOut[((size_t)bb2*S + tt)*512 + dir*256 + j] = hb;
    bar_arrive(mycnt);
  }
}

// ---------------------------------------------------------------------------
// Persistent decoder. Grid 256 = mg(2) x ng(128).
// Phase A (all): gates GEMM (cols [ng*16,+16), batches [mg*64,+64)), WD slice
//   in LDS; fused LSTM update (c in regs); out-projection of feed_{t-1} on
//   128 of the blocks. barA.
// Phase B: blocks 0-127 do attention (1 batch each); blocks 128-191 compute
//   the h-half of the feed GEMM concurrently. barB.
// Phase C: blocks 128-191 finish feed with the ctx-half + tanh. barC.
// ---------------------------------------------------------------------------
__global__ __launch_bounds__(256,1) void k_decoder(
  const unsigned short* __restrict__ win,    // (T,B,64)
  const unsigned short* __restrict__ WD,     // 2048x1088 (reordered rows j*4+g)
  const float* __restrict__ bD,              // 2048 reordered
  const unsigned short* __restrict__ WC,     // 512x1024
  const unsigned short* __restrict__ proj,   // (B,S,512)
  const unsigned short* __restrict__ encOut, // (B,S,512)
  const int* __restrict__ in_seq,
  const float* __restrict__ Wout, const float* __restrict__ bout,
  unsigned short* __restrict__ hdec,         // [2][B][512]
  unsigned short* __restrict__ feed,         // [B][512]
  unsigned short* __restrict__ ctxb,         // [B][512]
  float* __restrict__ out_main, float* __restrict__ out_attn,
  unsigned* __restrict__ cnts)               // +0 cA, +32 cB, +64 cC
{
  __shared__ __align__(16) unsigned short Ws[16*1096];
  __shared__ __align__(16) float scr[1152];  // union: Gs(64x17) | hsh512+red256+aw256
  unsigned* cA = cnts; unsigned* cB = cnts + 32; unsigned* cC = cnts + 64;
  const int bid = blockIdx.x;
  const int mg = bid >> 7, ng = bid & 127;
  const int tid = threadIdx.x;
  const int lane = tid & 63, w = tid >> 6;
  const int l16 = lane & 15, qd = lane >> 4;
  const int m_base = mg*64;
  float* Gs = scr;

  for (int i = tid; i < 16*136; i += 256){
    const int r = i / 136, s2 = i - r*136;
    *(uint4*)&Ws[r*1096 + s2*8] = *(const uint4*)&WD[((size_t)ng*16 + r)*1088 + s2*8];
  }
  const int bl = tid & 63, u = tid >> 6;
  const float b0 = bD[ng*16 + u*4 + 0];
  const float b1 = bD[ng*16 + u*4 + 1];
  const float b2 = bD[ng*16 + u*4 + 2];
  const float b3 = bD[ng*16 + u*4 + 3];
  float c = 0.f;
  const bool doOut  = (ng < 64);
  const int  b2o    = m_base + ng;           // outproj batch (when doOut)
  const bool doAttn = (bid < 128);
  const bool doFeed = (bid >= 128 && bid < 192);
  const int  f = bid & 127, fm = (f >> 5) & 1, fn = f & 31;
  __syncthreads();

  for (int t = 0; t < T; ++t){
    if (t) bar_wait(cC, (unsigned)(64u*(unsigned)t));   // feed_{t-1} ready
    // ---------------- phase A: gates + LSTM update ----------------
    const int row = m_base + w*16 + l16;
    const unsigned short* Aw = win  + ((size_t)t*B + row)*64 + qd*8;
    const unsigned short* Af = feed + (size_t)row*512 + qd*8;
    const unsigned short* Ah = hdec + ((size_t)(t&1)*B + row)*512 + qd*8;
    f32x4 acc = (f32x4){0.f,0.f,0.f,0.f};
#pragma unroll
    for (int ks = 0; ks < 2; ++ks){
      bf16x8 a  = *(const bf16x8*)(Aw + ks*32);
      bf16x8 bb = *(const bf16x8*)&Ws[l16*1096 + ks*32 + qd*8];
      acc = __builtin_amdgcn_mfma_f32_16x16x32_bf16(a, bb, acc, 0, 0, 0);
    }
#pragma unroll 8
    for (int ks = 0; ks < 16; ++ks){
      bf16x8 a  = *(const bf16x8*)(Af + ks*32);
      bf16x8 bb = *(const bf16x8*)&Ws[l16*1096 + 64 + ks*32 + qd*8];
      acc = __builtin_amdgcn_mfma_f32_16x16x32_bf16(a, bb, acc, 0, 0, 0);
    }
#pragma unroll 8
    for (int ks = 0; ks < 16; ++ks){
      bf16x8 a  = *(const bf16x8*)(Ah + ks*32);
      bf16x8 bb = *(const bf16x8*)&Ws[l16*1096 + 576 + ks*32 + qd*8];
      acc = __builtin_amdgcn_mfma_f32_16x16x32_bf16(a, bb, acc, 0, 0, 0);
    }
    __syncthreads();
#pragma unroll
    for (int r = 0; r < 4; ++r)
      Gs[(w*16 + qd*4 + r)*17 + l16] = acc[r];
    __syncthreads();
    {
      const float gi = Gs[bl*17 + u*4 + 0] + b0;
      const float gf = Gs[bl*17 + u*4 + 1] + b1;
      const float gg = Gs[bl*17 + u*4 + 2] + b2;
      const float go = Gs[bl*17 + u*4 + 3] + b3;
      const float cn = sigm(gf)*c + sigm(gi)*tanhf(gg);
      c = cn;
      const unsigned short hb = f2bf(sigm(go)*tanhf(cn));
      hdec[((size_t)((t+1)&1)*B + m_base + bl)*512 + ng*4 + u] = hb;
    }
    // out-projection of feed_{t-1} (feed not yet overwritten this step)
    if (doOut && t > 0){
      const int d = tid >> 6, kk = tid & 63;
      const unsigned short* fp = feed + (size_t)b2o*512 + kk*8;
      const float* wp = Wout + d*512 + kk*8;
      float p = 0.f;
#pragma unroll
      for (int j2 = 0; j2 < 8; ++j2) p += bf2f(fp[j2]) * wp[j2];
#pragma unroll
      for (int off = 32; off > 0; off >>= 1) p += __shfl_down(p, off, 64);
      if (kk == 0){
        const float v = p + bout[d];
        out_main[((size_t)b2o*T + (t-1))*4 + d] = (d < 3) ? tanhf(v) : fmaxf(v, 0.f);
      }
    }
    bar_arrive(cA);
    // ---------------- phase B / C ----------------
    if (doAttn){
      bar_wait(cA, (unsigned)(256u*(unsigned)(t+1)));   // full h_t
      const int b = bid;
      float* hsh = scr; float* red = scr + 512; float* awsh = scr + 768;
      const unsigned short* hsrc = hdec + ((size_t)((t+1)&1)*B + b)*512;
      hsh[tid]       = bf2f(hsrc[tid]);
      hsh[tid + 256] = bf2f(hsrc[tid + 256]);
      __syncthreads();
      const int s = tid;
      const uint4* pr = (const uint4*)(proj + ((size_t)b*S + s)*512);
      float sc = 0.f;
#pragma unroll 4
      for (int i = 0; i < 64; ++i){
        const uint4 uu = pr[i];
        float f0,f1,f2,f3,f4,f5,f6,f7;
        unp2(uu.x,f0,f1); unp2(uu.y,f2,f3); unp2(uu.z,f4,f5); unp2(uu.w,f6,f7);
        const float* hh = &hsh[i*8];
        sc += hh[0]*f0 + hh[1]*f1 + hh[2]*f2 + hh[3]*f3
            + hh[4]*f4 + hh[5]*f5 + hh[6]*f6 + hh[7]*f7;
      }
      if (in_seq[b*S + s] == 0) sc = -1e30f;
      red[tid] = sc; __syncthreads();
      for (int o = 128; o > 0; o >>= 1){ if (tid < o) red[tid] = fmaxf(red[tid], red[tid+o]); __syncthreads(); }
      const float mx = red[0]; __syncthreads();
      const float e = __expf(sc - mx);
      red[tid] = e; __syncthreads();
      for (int o = 128; o > 0; o >>= 1){ if (tid < o) red[tid] += red[tid+o]; __syncthreads(); }
      const float aw = e / red[0];
      awsh[s] = aw;
      out_attn[((size_t)b*T + t)*S + s] = aw;
      __syncthreads();
      float a0 = 0.f, a1 = 0.f;
      for (int ss = 0; ss < 256; ++ss){
        const float wgt = awsh[ss];
        const unsigned short* er = encOut + ((size_t)b*S + ss)*512;
        a0 += wgt * bf2f(er[tid]);
        a1 += wgt * bf2f(er[tid + 256]);
      }
      ctxb[(size_t)b*512 + tid]       = f2bf(a0);
      ctxb[(size_t)b*512 + tid + 256] = f2bf(a1);
      bar_arrive(cB);
    } else if (doFeed){
      bar_wait(cA, (unsigned)(256u*(unsigned)(t+1)));   // full h_t
      const int frow = fm*64 + w*16 + l16;
      const unsigned short* Fh = hdec + ((size_t)((t+1)&1)*B + frow)*512 + qd*8;
      const unsigned short* Bw = WC + ((size_t)(fn*16 + l16))*1024 + qd*8;
      f32x4 fa = (f32x4){0.f,0.f,0.f,0.f};
#pragma unroll 8
      for (int ks = 0; ks < 16; ++ks){          // h half — overlaps attention
        bf16x8 a  = *(const bf16x8*)(Fh + ks*32);
        bf16x8 bb = *(const bf16x8*)(Bw + ks*32);
        fa = __builtin_amdgcn_mfma_f32_16x16x32_bf16(a, bb, fa, 0, 0, 0);
      }
      bar_wait(cB, (unsigned)(128u*(unsigned)(t+1)));   // ctx ready
      const unsigned short* Fc = ctxb + (size_t)frow*512 + qd*8;
#pragma unroll 8
      for (int ks = 0; ks < 16; ++ks){          // ctx half
        bf16x8 a  = *(const bf16x8*)(Fc + ks*32);
        bf16x8 bb = *(const bf16x8*)(Bw + 512 + ks*32);
        fa = __builtin_amdgcn_mfma_f32_16x16x32_bf16(a, bb, fa, 0, 0, 0);
      }
#pragma unroll
      for (int r = 0; r < 4; ++r){
        const int m = fm*64 + w*16 + qd*4 + r;
        feed[(size_t)m*512 + fn*16 + l16] = f2bf(tanhf(fa[r]));
      }
      bar_arrive(cC);
    }
  }
  // final out-projection (feed_255)
  if (doOut){
    bar_wait(cC, (unsigned)(64u*256u));
    const int d = tid >> 6, kk = tid & 63;
    const unsigned short* fp = feed + (size_t)b2o*512 + kk*8;
    const float* wp = Wout + d*512 + kk*8;
    float p = 0.f;
#pragma unroll
    for (int j2 = 0; j2 < 8; ++j2) p += bf2f(fp[j2]) * wp[j2];
#pragma unroll
    for (int off = 32; off > 0; off >>= 1) p += __shfl_down(p, off, 64);
    if (kk == 0){
      const float v = p + bout[d];
      out_main[((size_t)b2o*T + 255)*4 + d] = (d < 3) ? tanhf(v) : fmaxf(v, 0.f);
    }
  }
}

// ---------------- setup / builder kernels ----------------
__global__ __launch_bounds__(256) void k_build_encw(
  const float* __restrict__ WihF, const float* __restrict__ WhhF,
  const float* __restrict__ WihB, const float* __restrict__ WhhB,
  unsigned short* WF, unsigned short* WB)
{
  const int idx = blockIdx.x*256 + threadIdx.x;     // 2*1024*512
  const int dir = idx >> 19;
  const int i2 = idx & 524287;
  const int row = i2 >> 9, col = i2 & 511;
  const int j = row >> 2, g = row & 3;
  const int orig = g*256 + j;
  const float* Wih = dir ? WihB : WihF;
  const float* Whh = dir ? WhhB : WhhF;
  const float v = (col < 256) ? Wih[orig*256 + col] : Whh[orig*256 + (col-256)];
  (dir ? WB : WF)[i2] = f2bf(v);
}

__global__ __launch_bounds__(256) void k_build_decw(
  const float* __restrict__ Wih, const float* __restrict__ Whh, unsigned short* WD)
{
  const int idx = blockIdx.x*256 + threadIdx.x;
  if (idx >= 2048*1088) return;
  const int row = idx / 1088, col = idx - row*1088;
  const int j = row >> 2, g = row & 3;
  const int orig = g*512 + j;
  float v;
  if (col < 16)        v = Wih[orig*528 + col];          // w_t part
  else if (col < 64)   v = 0.f;                          // pad
  else if (col < 576)  v = Wih[orig*528 + (col - 48)];   // feed part (cols 16..527)
  else                 v = Whh[orig*512 + (col - 576)];  // h part
  WD[idx] = f2bf(v);
}

__global__ __launch_bounds__(256) void k_build_plainw(
  const float* __restrict__ Wctx, const float* __restrict__ Wsrc,
  unsigned short* WC, unsigned short* WS)
{
  const int idx = blockIdx.x*256 + threadIdx.x;     // 512*1024 + 512*512
  if (idx < 524288) WC[idx] = f2bf(Wctx[idx]);
  else { const int i = idx - 524288; WS[i] = f2bf(Wsrc[i]); }
}

__global__ __launch_bounds__(256) void k_build_bias(
  const float* __restrict__ ebF, const float* __restrict__ ebB,
  const float* __restrict__ dB, float* bF, float* bB, float* bD)
{
  const int idx = blockIdx.x*256 + threadIdx.x;     // 4096
  if (idx < 1024) bF[idx] = ebF[(idx&3)*256 + (idx>>2)];
  else if (idx < 2048){ const int i = idx-1024; bB[i] = ebB[(i&3)*256 + (i>>2)]; }
  else { const int i = idx-2048; bD[i] = dB[(i&3)*512 + (i>>2)]; }
}

__global__ __launch_bounds__(256) void k_embed(
  const int* __restrict__ in_seq, const float* __restrict__ table, unsigned short* emb)
{
  const int idx = blockIdx.x*256 + threadIdx.x;     // S*B*256, layout (S,B,E)
  const int e = idx & 255, b = (idx >> 8) & 127, s = idx >> 15;
  const int tok = in_seq[b*S + s];
  emb[idx] = f2bf(table[(size_t)tok*256 + e]);
}

__global__ __launch_bounds__(256) void k_win(
  const float* __restrict__ tgt, unsigned short* win)
{
  const int idx = blockIdx.x*256 + threadIdx.x;     // T*B*64, layout (T,B,64)
  const int c = idx & 63, b = (idx >> 6) & 127, t = idx >> 13;
  float v = 0.f;
  if (c < 16){
    const int k = c >> 2, jj = c & 3;
    const int ts = t + k - 4;
    if (ts >= 0) v = tgt[((size_t)b*T + ts)*4 + jj];
  }
  win[idx] = f2bf(v);
}

// ---------------------------------------------------------------------------
extern "C" void kernel_launch(void* const* d_in, const int* in_sizes, int n_in,
                              void* d_out, int out_size, void* d_ws, size_t ws_size,
                              hipStream_t stream)
{
  const int*   in_seq    = (const int*)d_in[0];
  const float* tgt       = (const float*)d_in[1];
  // d_in[2] = lengths (unused by reference)
  const float* embedding = (const float*)d_in[3];
  const float* eWihF = (const float*)d_in[4];
  const float* eWhhF = (const float*)d_in[5];
  const float* ebF   = (const float*)d_in[6];
  const float* eWihB = (const float*)d_in[7];
  const float* eWhhB = (const float*)d_in[8];
  const float* ebB   = (const float*)d_in[9];
  const float* dWih  = (const float*)d_in[10];
  const float* dWhh  = (const float*)d_in[11];
  const float* dB    = (const float*)d_in[12];
  const float* Wsrc  = (const float*)d_in[13];
  const float* Wctx  = (const float*)d_in[14];
  const float* Wout  = (const float*)d_in[15];
  const float* bout  = (const float*)d_in[16];

  char* ws = (char*)d_ws;
  size_t off = 0;
  auto al = [&](size_t bytes)->char*{
    char* p = ws + off; off += (bytes + 255) & ~(size_t)255; return p; };

  // --- state region (zeroed every launch with one memset) ---
  char* stateBase = ws;
  unsigned short* hEnc = (unsigned short*)al(262144);  // [2][2][128][256]
  unsigned short* hdec = (unsigned short*)al(262144);  // [2][128][512]
  unsigned short* feed = (unsigned short*)al(131072);  // [128][512]
  unsigned short* ctxb = (unsigned short*)al(131072);  // [128][512]
  unsigned*       cnts = (unsigned*)al(1024);          // barrier counters
  const size_t stateBytes = off;

  // --- persistent-per-launch scratch ---
  unsigned short* emb    = (unsigned short*)al(16777216);  // (S,B,256) bf16
  unsigned short* win    = (unsigned short*)al(4194304);   // (T,B,64) bf16
  unsigned short* encOut = (unsigned short*)al(33554432);  // (B,S,512) bf16
  unsigned short* proj   = (unsigned short*)al(33554432);  // (B,S,512) bf16
  unsigned short* WF     = (unsigned short*)al(1048576);   // 1024x512
  unsigned short* WB     = (unsigned short*)al(1048576);
  unsigned short* WD     = (unsigned short*)al(4456448);   // 2048x1088
  unsigned short* WC     = (unsigned short*)al(1048576);   // 512x1024
  unsigned short* WS     = (unsigned short*)al(524288);    // 512x512
  float* bFr = (float*)al(4096);
  float* bBr = (float*)al(4096);
  float* bDr = (float*)al(8192);
  (void)ws_size; (void)in_sizes; (void)n_in; (void)out_size;

  float* out_main = (float*)d_out;
  float* out_attn = out_main + (size_t)B*T*DOF;

  const dim3 blk(256);
  k_build_encw  <<<4096,  blk, 0, stream>>>(eWihF, eWhhF, eWihB, eWhhB, WF, WB);
  k_build_decw  <<<8704,  blk, 0, stream>>>(dWih, dWhh, WD);
  k_build_plainw<<<3072,  blk, 0, stream>>>(Wctx, Wsrc, WC, WS);
  k_build_bias  <<<16,    blk, 0, stream>>>(ebF, ebB, dB, bFr, bBr, bDr);
  k_embed       <<<32768, blk, 0, stream>>>(in_seq, embedding, emb);
  k_win         <<<8192,  blk, 0, stream>>>(tgt, win);
  hipMemsetAsync(stateBase, 0, stateBytes, stream);

  // persistent encoder: 256 steps internally
  k_encoder<<<256, blk, 0, stream>>>(emb, WF, WB, bFr, bBr, hEnc, encOut, cnts + 96);

  // proj = enc_out @ W_src^T  (M=32768, N=512, K=512) — fully parallel
  k_gemm_plain<<<8192, blk, 0, stream>>>(encOut, 512, 512, nullptr, 0, 0,
                                         WS, 512, 16, proj, 512, 0);

  // persistent decoder: 256 steps internally
  k_decoder<<<256, blk, 0, stream>>>(win, WD, bDr, WC, proj, encOut, in_seq,
                                     Wout, bout, hdec, feed, ctxb,
                                     out_main, out_attn, cnts);
}

// Round 3
// 14131.429 us; speedup vs baseline: 5.8211x; 5.8211x over previous
//
#include <hip/hip_runtime.h>
#include <stdint.h>

// Problem constants (match reference)
#define B 128
#define S 256
#define T 256
#define EMBED 256
#define ENC 256
#define DEC 512
#define DOF 4

typedef __attribute__((ext_vector_type(8))) short bf16x8;   // 8 bf16 = 4 VGPRs (MFMA A/B frag)
typedef __attribute__((ext_vector_type(4))) float f32x4;    // MFMA C/D frag

static __device__ __forceinline__ float bf2f(unsigned short u){
  union{uint32_t u;float f;}c; c.u = ((uint32_t)u)<<16; return c.f;
}
static __device__ __forceinline__ unsigned short f2bf(float f){
  union{float f;uint32_t u;}c; c.f=f; uint32_t u=c.u;
  u += 0x7fffu + ((u>>16)&1u);  // round-to-nearest-even
  return (unsigned short)(u>>16);
}
static __device__ __forceinline__ void unp2(uint32_t w, float&a, float&b){
  union{uint32_t u;float f;}c1,c2; c1.u = w<<16; c2.u = w & 0xffff0000u; a=c1.f; b=c2.f;
}
static __device__ __forceinline__ float sigm(float x){ return 1.0f/(1.0f+__expf(-x)); }

// ---------------------------------------------------------------------------
// Coherent (agent-scope, cache-bypassing) accessors for cross-block state.
// Relaxed atomics lower to sc0/sc1-flagged global ops: no buffer_inv, no wbl2
// -> the per-XCD L2 keeps read-only data (proj/encOut/weights) hot.
// ---------------------------------------------------------------------------
static __device__ __forceinline__ unsigned long long ldc8(const void* p){
  return __hip_atomic_load((unsigned long long*)p, __ATOMIC_RELAXED, __HIP_MEMORY_SCOPE_AGENT);
}
static __device__ __forceinline__ void stc8(void* p, unsigned long long v){
  __hip_atomic_store((unsigned long long*)p, v, __ATOMIC_RELAXED, __HIP_MEMORY_SCOPE_AGENT);
}
static __device__ __forceinline__ void stc4(void* p, unsigned v){
  __hip_atomic_store((unsigned*)p, v, __ATOMIC_RELAXED, __HIP_MEMORY_SCOPE_AGENT);
}
union F16x8 { unsigned long long q[2]; bf16x8 v; };
static __device__ __forceinline__ bf16x8 ldfrag_c(const unsigned short* p){
  F16x8 u;
  u.q[0] = ldc8(p);
  u.q[1] = ldc8(p + 4);
  return u.v;
}
static __device__ __forceinline__ unsigned long long pack4bf(float a,float b,float c,float d){
  return (unsigned long long)f2bf(a) | ((unsigned long long)f2bf(b)<<16)
       | ((unsigned long long)f2bf(c)<<32) | ((unsigned long long)f2bf(d)<<48);
}

// ---------------------------------------------------------------------------
// Device-scope monotonic barrier, relaxed polling (no per-poll cache inv).
// Producer: data written via stc*/coherent stores -> waitcnt drains them ->
// s_barrier -> one relaxed add. Consumer: relaxed poll, then coherent loads.
// ---------------------------------------------------------------------------
static __device__ __forceinline__ void bar_arrive(unsigned* cnt){
  __builtin_amdgcn_s_waitcnt(0);     // drain this wave's stores to coherent point
  __syncthreads();                   // all waves drained (compiler waits vm before s_barrier)
  if (threadIdx.x == 0)
    __hip_atomic_fetch_add(cnt, 1u, __ATOMIC_RELAXED, __HIP_MEMORY_SCOPE_AGENT);
}
static __device__ __forceinline__ void bar_wait(unsigned* cnt, unsigned target){
  if (threadIdx.x == 0){
    while (__hip_atomic_load(cnt, __ATOMIC_RELAXED, __HIP_MEMORY_SCOPE_AGENT) < target)
      __builtin_amdgcn_s_sleep(2);
  }
  __syncthreads();
  asm volatile("" ::: "memory");     // compiler-only fence: no reordering across barrier
}

// ---------------------------------------------------------------------------
// bf16 MFMA GEMM core for the (parallel) proj GEMM. 64x32 C tile.
// ---------------------------------------------------------------------------
static __device__ __forceinline__ void gemm_tile(
    const unsigned short* __restrict__ s0, int l0, int ld0,
    const unsigned short* __restrict__ W, int ldw,
    int m_base, int n_base, char* smem, f32x4* acc)
{
  unsigned short* As = (unsigned short*)smem;     // 64 x 72
  unsigned short* Bs = As + 64*72;                // 32 x 72
  const int tid  = threadIdx.x;
  const int lane = tid & 63;
  const int wid  = tid >> 6;
  const int wm = wid >> 1, wn = wid & 1;
  const int l16 = lane & 15, qd = lane >> 4;
  const int ar = tid >> 2, aco = (tid & 3) * 16;
  const int br = (tid & 127) >> 2, bco = (tid & 3) * 16;
  const bool loadB = (tid >= 128);

  for (int ktb = 0; ktb < l0; ktb += 64){
    const unsigned short* arow = s0 + (size_t)(m_base + ar) * ld0 + ktb + aco;
    uint4 av0 = *(const uint4*)(arow);
    uint4 av1 = *(const uint4*)(arow + 8);
    uint4 bv0, bv1;
    if (loadB){
      const unsigned short* brow = W + (size_t)(n_base + br) * ldw + ktb + bco;
      bv0 = *(const uint4*)(brow);
      bv1 = *(const uint4*)(brow + 8);
    }
    __syncthreads();
    *(uint4*)&As[ar*72 + aco]     = av0;
    *(uint4*)&As[ar*72 + aco + 8] = av1;
    if (loadB){
      *(uint4*)&Bs[br*72 + bco]     = bv0;
      *(uint4*)&Bs[br*72 + bco + 8] = bv1;
    }
    __syncthreads();
#pragma unroll
    for (int kh = 0; kh < 2; ++kh){
      const int ko = kh*32 + qd*8;
      bf16x8 a0 = *(bf16x8*)&As[(wm*32      + l16)*72 + ko];
      bf16x8 a1 = *(bf16x8*)&As[(wm*32 + 16 + l16)*72 + ko];
      bf16x8 bb = *(bf16x8*)&Bs[(wn*16      + l16)*72 + ko];
      acc[0] = __builtin_amdgcn_mfma_f32_16x16x32_bf16(a0, bb, acc[0], 0, 0, 0);
      acc[1] = __builtin_amdgcn_mfma_f32_16x16x32_bf16(a1, bb, acc[1], 0, 0, 0);
    }
  }
}

__global__ __launch_bounds__(256) void k_gemm_plain(
  const unsigned short* __restrict__ s0,int l0,int ld0,
  const unsigned short* __restrict__ W,int ldw,int ntiles,
  unsigned short* Cbf, int ldc)
{
  __shared__ __align__(16) char smem[13824];
  const int bid = blockIdx.x;
  const int mt = bid / ntiles, nt = bid % ntiles;
  const int m_base = mt*64, n_base = nt*32;
  f32x4 acc[2];
  acc[0] = (f32x4){0.f,0.f,0.f,0.f};
  acc[1] = (f32x4){0.f,0.f,0.f,0.f};
  gemm_tile(s0,l0,ld0, W,ldw, m_base,n_base, smem, acc);
  const int tid = threadIdx.x, lane = tid & 63, wid = tid >> 6;
  const int wm = wid >> 1, wn = wid & 1, l16 = lane & 15, qd = lane >> 4;
#pragma unroll
  for (int tl = 0; tl < 2; ++tl)
#pragma unroll
    for (int r = 0; r < 4; ++r){
      const int m = m_base + wm*32 + tl*16 + qd*4 + r;
      Cbf[(size_t)m*ldc + n_base + wn*16 + l16] = f2bf(acc[tl][r]);
    }
}

// ---------------------------------------------------------------------------
// Persistent bi-LSTM encoder. Grid 256 = dir(2) x mg(2) x ng(64).
// Weight slice (16x512) in LDS all 256 steps; c in registers (4/thread on
// threads 0..63). h via coherent 8B atomics; emb/encOut normal (read-only /
// flushed at kernel end).
// ---------------------------------------------------------------------------
__global__ __launch_bounds__(256,1) void k_encoder(
  const unsigned short* __restrict__ emb,   // (S,B,256)
  const unsigned short* __restrict__ WF, const unsigned short* __restrict__ WB,
  const float* __restrict__ bF, const float* __restrict__ bB,
  unsigned short* __restrict__ hEnc,        // [dir][2][B][256]
  unsigned short* __restrict__ encOut,      // [B][S][512]
  unsigned* __restrict__ cnt)               // +0: fwd, +32: bwd
{
  __shared__ __align__(16) unsigned short Ws[16*520];
  __shared__ __align__(16) float Gs[64*17];
  __shared__ float bsh[16];
  const int bid = blockIdx.x;
  const int dir = bid >> 7;
  const int mg  = (bid >> 6) & 1;
  const int ng  = bid & 63;
  const int tid = threadIdx.x;
  const int lane = tid & 63, w = tid >> 6;
  const int l16 = lane & 15, qd = lane >> 4;
  const int m_base = mg * 64;
  unsigned* mycnt = cnt + dir*32;

  const unsigned short* Wg = (dir ? WB : WF) + (size_t)ng*16*512;
  for (int i = tid; i < 16*64; i += 256){
    const int r = i >> 6, s = i & 63;
    *(uint4*)&Ws[r*520 + s*8] = *(const uint4*)&Wg[r*512 + s*8];
  }
  if (tid < 16) bsh[tid] = (dir ? bB : bF)[ng*16 + tid];
  float c[4] = {0.f,0.f,0.f,0.f};
  __syncthreads();

  for (int t = 0; t < S; ++t){
    if (t) bar_wait(mycnt, (unsigned)(128u*(unsigned)t));
    const int tt = dir ? (S-1-t) : t;
    const unsigned short* Ae = emb + ((size_t)tt*B + m_base + w*16 + l16)*256 + qd*8;
    const unsigned short* Ah = hEnc + (((size_t)dir*2 + (size_t)(t&1))*B + m_base + w*16 + l16)*256 + qd*8;
    bf16x8 hf[8];
#pragma unroll
    for (int ks = 0; ks < 8; ++ks) hf[ks] = ldfrag_c(Ah + ks*32);
    f32x4 acc = (f32x4){0.f,0.f,0.f,0.f};
#pragma unroll
    for (int ks = 0; ks < 8; ++ks){
      bf16x8 a  = *(const bf16x8*)(Ae + ks*32);
      bf16x8 bb = *(const bf16x8*)&Ws[l16*520 + ks*32 + qd*8];
      acc = __builtin_amdgcn_mfma_f32_16x16x32_bf16(a, bb, acc, 0, 0, 0);
    }
#pragma unroll
    for (int ks = 0; ks < 8; ++ks){
      bf16x8 bb = *(const bf16x8*)&Ws[l16*520 + 256 + ks*32 + qd*8];
      acc = __builtin_amdgcn_mfma_f32_16x16x32_bf16(hf[ks], bb, acc, 0, 0, 0);
    }
    __syncthreads();
#pragma unroll
    for (int r = 0; r < 4; ++r)
      Gs[(w*16 + qd*4 + r)*17 + l16] = acc[r];
    __syncthreads();
    if (tid < 64){
      const int bl = tid;
      float hv[4];
#pragma unroll
      for (int u = 0; u < 4; ++u){
        const float gi = Gs[bl*17 + u*4 + 0] + bsh[u*4 + 0];
        const float gf = Gs[bl*17 + u*4 + 1] + bsh[u*4 + 1];
        const float gg = Gs[bl*17 + u*4 + 2] + bsh[u*4 + 2];
        const float go = Gs[bl*17 + u*4 + 3] + bsh[u*4 + 3];
        const float cn = sigm(gf)*c[u] + sigm(gi)*tanhf(gg);
        c[u] = cn;
        hv[u] = sigm(go)*tanhf(cn);
      }
      const int b2 = m_base + bl;
      const unsigned long long hq = pack4bf(hv[0],hv[1],hv[2],hv[3]);
      stc8(&hEnc[(((size_t)dir*2 + (size_t)((t+1)&1))*B + b2)*256 + ng*4], hq);
      *(unsigned long long*)&encOut[((size_t)b2*S + tt)*512 + dir*256 + ng*4] = hq;
    }
    bar_arrive(mycnt);
  }
}

// ---------------------------------------------------------------------------
// Persistent decoder. Grid 256 = mg(2) x ng(128). 3 barriers/step:
//  A (all): gates GEMM (WD slice in LDS, coherent A prefetch) + LSTM update
//           + out-proj of feed_{t-1} on 128 blocks. barA.
//  B: blocks 0-127 attention (per-batch, vectorized); 128-191 feed h-half.
//  C: blocks 128-191 feed ctx-half + tanh. barC -> next step.
// ---------------------------------------------------------------------------
__global__ __launch_bounds__(256,1) void k_decoder(
  const unsigned short* __restrict__ win,    // (T,B,64)
  const unsigned short* __restrict__ WD,     // 2048x1088 (rows j*4+g)
  const float* __restrict__ bD,              // 2048 reordered
  const unsigned short* __restrict__ WC,     // 512x1024
  const unsigned short* __restrict__ proj,   // (B,S,512)
  const unsigned short* __restrict__ encOut, // (B,S,512)
  const int* __restrict__ in_seq,
  const float* __restrict__ Wout, const float* __restrict__ bout,
  unsigned short* __restrict__ hdec,         // [2][B][512]
  unsigned short* __restrict__ feed,         // [B][512]
  unsigned short* __restrict__ ctxb,         // [B][512]
  float* __restrict__ out_main, float* __restrict__ out_attn,
  unsigned* __restrict__ cnts)               // +0 cA, +32 cB, +64 cC
{
  __shared__ __align__(16) unsigned short Ws[16*1096];   // gates WD slice
  __shared__ __align__(16) unsigned short WCs[16*1032];  // feed WC slice
  __shared__ __align__(16) float scr[3072];
  __shared__ float bsh[16];
  unsigned* cA = cnts; unsigned* cB = cnts + 32; unsigned* cC = cnts + 64;
  const int bid = blockIdx.x;
  const int mg = bid >> 7, ng = bid & 127;
  const int tid = threadIdx.x;
  const int lane = tid & 63, w = tid >> 6;
  const int l16 = lane & 15, qd = lane >> 4;
  const int m_base = mg*64;
  float* Gs = scr;

  for (int i = tid; i < 16*136; i += 256){
    const int r = i / 136, s2 = i - r*136;
    *(uint4*)&Ws[r*1096 + s2*8] = *(const uint4*)&WD[((size_t)ng*16 + r)*1088 + s2*8];
  }
  if (tid < 16) bsh[tid] = bD[ng*16 + tid];
  const bool doOut  = (ng < 64);
  const int  b2o    = m_base + ng;           // outproj batch (when doOut)
  const bool doAttn = (bid < 128);
  const bool doFeed = (bid >= 128 && bid < 192);
  const int  f = bid & 127, fm = (f >> 5) & 1, fn = f & 31;
  if (doFeed){
    for (int i = tid; i < 16*128; i += 256){
      const int r = i >> 7, s2 = i & 127;
      *(uint4*)&WCs[r*1032 + s2*8] = *(const uint4*)&WC[((size_t)(fn*16 + r))*1024 + s2*8];
    }
  }
  float c[4] = {0.f,0.f,0.f,0.f};
  __syncthreads();

  for (int t = 0; t < T; ++t){
    if (t) bar_wait(cC, (unsigned)(64u*(unsigned)t));   // feed_{t-1} ready
    // ---------------- phase A: gates + LSTM update ----------------
    const int row = m_base + w*16 + l16;
    const unsigned short* Aw = win  + ((size_t)t*B + row)*64 + qd*8;
    const unsigned short* Af = feed + (size_t)row*512 + qd*8;
    const unsigned short* Ah = hdec + ((size_t)(t&1)*B + row)*512 + qd*8;
    bf16x8 ff[16], hh[16];
#pragma unroll
    for (int ks = 0; ks < 16; ++ks) ff[ks] = ldfrag_c(Af + ks*32);
#pragma unroll
    for (int ks = 0; ks < 16; ++ks) hh[ks] = ldfrag_c(Ah + ks*32);
    f32x4 acc = (f32x4){0.f,0.f,0.f,0.f};
#pragma unroll
    for (int ks = 0; ks < 2; ++ks){
      bf16x8 a  = *(const bf16x8*)(Aw + ks*32);
      bf16x8 bb = *(const bf16x8*)&Ws[l16*1096 + ks*32 + qd*8];
      acc = __builtin_amdgcn_mfma_f32_16x16x32_bf16(a, bb, acc, 0, 0, 0);
    }
#pragma unroll
    for (int ks = 0; ks < 16; ++ks){
      bf16x8 bb = *(const bf16x8*)&Ws[l16*1096 + 64 + ks*32 + qd*8];
      acc = __builtin_amdgcn_mfma_f32_16x16x32_bf16(ff[ks], bb, acc, 0, 0, 0);
    }
#pragma unroll
    for (int ks = 0; ks < 16; ++ks){
      bf16x8 bb = *(const bf16x8*)&Ws[l16*1096 + 576 + ks*32 + qd*8];
      acc = __builtin_amdgcn_mfma_f32_16x16x32_bf16(hh[ks], bb, acc, 0, 0, 0);
    }
    __syncthreads();
#pragma unroll
    for (int r = 0; r < 4; ++r)
      Gs[(w*16 + qd*4 + r)*17 + l16] = acc[r];
    __syncthreads();
    if (tid < 64){
      const int bl = tid;
      float hv[4];
#pragma unroll
      for (int u = 0; u < 4; ++u){
        const float gi = Gs[bl*17 + u*4 + 0] + bsh[u*4 + 0];
        const float gf = Gs[bl*17 + u*4 + 1] + bsh[u*4 + 1];
        const float gg = Gs[bl*17 + u*4 + 2] + bsh[u*4 + 2];
        const float go = Gs[bl*17 + u*4 + 3] + bsh[u*4 + 3];
        const float cn = sigm(gf)*c[u] + sigm(gi)*tanhf(gg);
        c[u] = cn;
        hv[u] = sigm(go)*tanhf(cn);
      }
      stc8(&hdec[((size_t)((t+1)&1)*B + m_base + bl)*512 + ng*4],
           pack4bf(hv[0],hv[1],hv[2],hv[3]));
    }
    // out-projection of feed_{t-1}
    if (doOut && t > 0){
      const int d = tid >> 6, kk = tid & 63;
      const unsigned short* fp = feed + (size_t)b2o*512 + kk*8;
      F16x8 u; u.q[0] = ldc8(fp); u.q[1] = ldc8(fp + 4);
      const float* wp = Wout + d*512 + kk*8;
      float p = 0.f;
#pragma unroll
      for (int j2 = 0; j2 < 8; ++j2) p += bf2f(((unsigned short*)&u)[j2]) * wp[j2];
#pragma unroll
      for (int off = 32; off > 0; off >>= 1) p += __shfl_down(p, off, 64);
      if (kk == 0){
        const float v = p + bout[d];
        out_main[((size_t)b2o*T + (t-1))*4 + d] = (d < 3) ? tanhf(v) : fmaxf(v, 0.f);
      }
    }
    bar_arrive(cA);
    // ---------------- phase B / C ----------------
    if (doAttn){
      bar_wait(cA, (unsigned)(256u*(unsigned)(t+1)));   // full h_t
      const int b = bid;
      float* hsh = scr; float* red = scr + 512; float* awsh = scr + 768;
      float* part = scr + 1024;
      const unsigned short* hsrc = hdec + ((size_t)((t+1)&1)*B + b)*512;
      if (tid < 128){
        F16x8 u; u.q[0] = ldc8(hsrc + tid*4); u.q[1] = 0;
#pragma unroll
        for (int j2 = 0; j2 < 4; ++j2) hsh[tid*4 + j2] = bf2f(((unsigned short*)&u)[j2]);
      }
      __syncthreads();
      // scores
      const int s = tid;
      const uint4* pr = (const uint4*)(proj + ((size_t)b*S + s)*512);
      float sc = 0.f;
#pragma unroll 4
      for (int i = 0; i < 64; ++i){
        const uint4 uu = pr[i];
        float f0,f1,f2,f3,f4,f5,f6,f7;
        unp2(uu.x,f0,f1); unp2(uu.y,f2,f3); unp2(uu.z,f4,f5); unp2(uu.w,f6,f7);
        const float* hhp = &hsh[i*8];
        sc += hhp[0]*f0 + hhp[1]*f1 + hhp[2]*f2 + hhp[3]*f3
            + hhp[4]*f4 + hhp[5]*f5 + hhp[6]*f6 + hhp[7]*f7;
      }
      if (in_seq[b*S + s] == 0) sc = -1e30f;
      red[tid] = sc; __syncthreads();
      for (int o = 128; o > 0; o >>= 1){ if (tid < o) red[tid] = fmaxf(red[tid], red[tid+o]); __syncthreads(); }
      const float mx = red[0]; __syncthreads();
      const float e = __expf(sc - mx);
      red[tid] = e; __syncthreads();
      for (int o = 128; o > 0; o >>= 1){ if (tid < o) red[tid] += red[tid+o]; __syncthreads(); }
      const float aw = e / red[0];
      awsh[s] = aw;
      __builtin_nontemporal_store(aw, &out_attn[((size_t)b*T + t)*S + s]);
      __syncthreads();
      // ctx: wave w covers ss in [w*64, w*64+64); lane owns e-chunk lane*8..+8
      float a[8] = {0,0,0,0,0,0,0,0};
      const unsigned short* eb = encOut + (size_t)b*S*512 + lane*8;
      for (int i = 0; i < 64; ++i){
        const int ss = w*64 + i;
        const float wgt = awsh[ss];
        const uint4 uu = *(const uint4*)(eb + (size_t)ss*512);
        float f0,f1,f2,f3,f4,f5,f6,f7;
        unp2(uu.x,f0,f1); unp2(uu.y,f2,f3); unp2(uu.z,f4,f5); unp2(uu.w,f6,f7);
        a[0]+=wgt*f0; a[1]+=wgt*f1; a[2]+=wgt*f2; a[3]+=wgt*f3;
        a[4]+=wgt*f4; a[5]+=wgt*f5; a[6]+=wgt*f6; a[7]+=wgt*f7;
      }
#pragma unroll
      for (int j2 = 0; j2 < 8; ++j2) part[w*512 + lane*8 + j2] = a[j2];
      __syncthreads();
      {
        const int e2 = tid*2;
        float s0 = part[e2] + part[512+e2] + part[1024+e2] + part[1536+e2];
        float s1 = part[e2+1] + part[512+e2+1] + part[1024+e2+1] + part[1536+e2+1];
        stc4(&ctxb[(size_t)b*512 + e2],
             (unsigned)f2bf(s0) | ((unsigned)f2bf(s1) << 16));
      }
      bar_arrive(cB);
    } else if (doFeed){
      bar_wait(cA, (unsigned)(256u*(unsigned)(t+1)));   // full h_t
      const int frow = fm*64 + w*16 + l16;
      const unsigned short* Fh = hdec + ((size_t)((t+1)&1)*B + frow)*512 + qd*8;
      bf16x8 hp[16];
#pragma unroll
      for (int ks = 0; ks < 16; ++ks) hp[ks] = ldfrag_c(Fh + ks*32);
      f32x4 fa = (f32x4){0.f,0.f,0.f,0.f};
#pragma unroll
      for (int ks = 0; ks < 16; ++ks){          // h half — overlaps attention
        bf16x8 bb = *(const bf16x8*)&WCs[l16*1032 + ks*32 + qd*8];
        fa = __builtin_amdgcn_mfma_f32_16x16x32_bf16(hp[ks], bb, fa, 0, 0, 0);
      }
      bar_wait(cB, (unsigned)(128u*(unsigned)(t+1)));   // ctx ready
      const unsigned short* Fc = ctxb + (size_t)frow*512 + qd*8;
      bf16x8 cp[16];
#pragma unroll
      for (int ks = 0; ks < 16; ++ks) cp[ks] = ldfrag_c(Fc + ks*32);
#pragma unroll
      for (int ks = 0; ks < 16; ++ks){          // ctx half
        bf16x8 bb = *(const bf16x8*)&WCs[l16*1032 + 512 + ks*32 + qd*8];
        fa = __builtin_amdgcn_mfma_f32_16x16x32_bf16(cp[ks], bb, fa, 0, 0, 0);
      }
      // stage to LDS (transpose to row-contiguous), then packed coherent stores
      __syncthreads();
#pragma unroll
      for (int r = 0; r < 4; ++r)
        scr[(w*16 + qd*4 + r)*16 + l16] = tanhf(fa[r]);
      __syncthreads();
      {
        const int rr = tid >> 2, cg = tid & 3;
        const float* sp = &scr[rr*16 + cg*4];
        stc8(&feed[(size_t)(fm*64 + rr)*512 + fn*16 + cg*4],
             pack4bf(sp[0], sp[1], sp[2], sp[3]));
      }
      bar_arrive(cC);
    }
  }
  // final out-projection (feed_255)
  if (doOut){
    bar_wait(cC, (unsigned)(64u*256u));
    const int d = tid >> 6, kk = tid & 63;
    const unsigned short* fp = feed + (size_t)b2o*512 + kk*8;
    F16x8 u; u.q[0] = ldc8(fp); u.q[1] = ldc8(fp + 4);
    const float* wp = Wout + d*512 + kk*8;
    float p = 0.f;
#pragma unroll
    for (int j2 = 0; j2 < 8; ++j2) p += bf2f(((unsigned short*)&u)[j2]) * wp[j2];
#pragma unroll
    for (int off = 32; off > 0; off >>= 1) p += __shfl_down(p, off, 64);
    if (kk == 0){
      const float v = p + bout[d];
      out_main[((size_t)b2o*T + 255)*4 + d] = (d < 3) ? tanhf(v) : fmaxf(v, 0.f);
    }
  }
}

// ---------------- setup / builder kernels ----------------
__global__ __launch_bounds__(256) void k_build_encw(
  const float* __restrict__ WihF, const float* __restrict__ WhhF,
  const float* __restrict__ WihB, const float* __restrict__ WhhB,
  unsigned short* WF, unsigned short* WB)
{
  const int idx = blockIdx.x*256 + threadIdx.x;     // 2*1024*512
  const int dir = idx >> 19;
  const int i2 = idx & 524287;
  const int row = i2 >> 9, col = i2 & 511;
  const int j = row >> 2, g = row & 3;
  const int orig = g*256 + j;
  const float* Wih = dir ? WihB : WihF;
  const float* Whh = dir ? WhhB : WhhF;
  const float v = (col < 256) ? Wih[orig*256 + col] : Whh[orig*256 + (col-256)];
  (dir ? WB : WF)[i2] = f2bf(v);
}

__global__ __launch_bounds__(256) void k_build_decw(
  const float* __restrict__ Wih, const float* __restrict__ Whh, unsigned short* WD)
{
  const int idx = blockIdx.x*256 + threadIdx.x;
  if (idx >= 2048*1088) return;
  const int row = idx / 1088, col = idx - row*1088;
  const int j = row >> 2, g = row & 3;
  const int orig = g*512 + j;
  float v;
  if (col < 16)        v = Wih[orig*528 + col];          // w_t part
  else if (col < 64)   v = 0.f;                          // pad
  else if (col < 576)  v = Wih[orig*528 + (col - 48)];   // feed part
  else                 v = Whh[orig*512 + (col - 576)];  // h part
  WD[idx] = f2bf(v);
}

__global__ __launch_bounds__(256) void k_build_plainw(
  const float* __restrict__ Wctx, const float* __restrict__ Wsrc,
  unsigned short* WC, unsigned short* WS)
{
  const int idx = blockIdx.x*256 + threadIdx.x;     // 512*1024 + 512*512
  if (idx < 524288) WC[idx] = f2bf(Wctx[idx]);
  else { const int i = idx - 524288; WS[i] = f2bf(Wsrc[i]); }
}

__global__ __launch_bounds__(256) void k_build_bias(
  const float* __restrict__ ebF, const float* __restrict__ ebB,
  const float* __restrict__ dB, float* bF, float* bB, float* bD)
{
  const int idx = blockIdx.x*256 + threadIdx.x;     // 4096
  if (idx < 1024) bF[idx] = ebF[(idx&3)*256 + (idx>>2)];
  else if (idx < 2048){ const int i = idx-1024; bB[i] = ebB[(i&3)*256 + (i>>2)]; }
  else { const int i = idx-2048; bD[i] = dB[(i&3)*512 + (i>>2)]; }
}

__global__ __launch_bounds__(256) void k_embed(
  const int* __restrict__ in_seq, const float* __restrict__ table, unsigned short* emb)
{
  const int idx = blockIdx.x*256 + threadIdx.x;     // S*B*256, layout (S,B,E)
  const int e = idx & 255, b = (idx >> 8) & 127, s = idx >> 15;
  const int tok = in_seq[b*S + s];
  emb[idx] = f2bf(table[(size_t)tok*256 + e]);
}

__global__ __launch_bounds__(256) void k_win(
  const float* __restrict__ tgt, unsigned short* win)
{
  const int idx = blockIdx.x*256 + threadIdx.x;     // T*B*64, layout (T,B,64)
  const int c = idx & 63, b = (idx >> 6) & 127, t = idx >> 13;
  float v = 0.f;
  if (c < 16){
    const int k = c >> 2, jj = c & 3;
    const int ts = t + k - 4;
    if (ts >= 0) v = tgt[((size_t)b*T + ts)*4 + jj];
  }
  win[idx] = f2bf(v);
}

// ---------------------------------------------------------------------------
extern "C" void kernel_launch(void* const* d_in, const int* in_sizes, int n_in,
                              void* d_out, int out_size, void* d_ws, size_t ws_size,
                              hipStream_t stream)
{
  const int*   in_seq    = (const int*)d_in[0];
  const float* tgt       = (const float*)d_in[1];
  // d_in[2] = lengths (unused by reference)
  const float* embedding = (const float*)d_in[3];
  const float* eWihF = (const float*)d_in[4];
  const float* eWhhF = (const float*)d_in[5];
  const float* ebF   = (const float*)d_in[6];
  const float* eWihB = (const float*)d_in[7];
  const float* eWhhB = (const float*)d_in[8];
  const float* ebB   = (const float*)d_in[9];
  const float* dWih  = (const float*)d_in[10];
  const float* dWhh  = (const float*)d_in[11];
  const float* dB    = (const float*)d_in[12];
  const float* Wsrc  = (const float*)d_in[13];
  const float* Wctx  = (const float*)d_in[14];
  const float* Wout  = (const float*)d_in[15];
  const float* bout  = (const float*)d_in[16];

  char* ws = (char*)d_ws;
  size_t off = 0;
  auto al = [&](size_t bytes)->char*{
    char* p = ws + off; off += (bytes + 255) & ~(size_t)255; return p; };

  // --- state region (zeroed every launch with one memset) ---
  char* stateBase = ws;
  unsigned short* hEnc = (unsigned short*)al(262144);  // [2][2][128][256]
  unsigned short* hdec = (unsigned short*)al(262144);  // [2][128][512]
  unsigned short* feed = (unsigned short*)al(131072);  // [128][512]
  unsigned short* ctxb = (unsigned short*)al(131072);  // [128][512]
  unsigned*       cnts = (unsigned*)al(1024);          // barrier counters
  const size_t stateBytes = off;

  // --- persistent-per-launch scratch ---
  unsigned short* emb    = (unsigned short*)al(16777216);  // (S,B,256) bf16
  unsigned short* win    = (unsigned short*)al(4194304);   // (T,B,64) bf16
  unsigned short* encOut = (unsigned short*)al(33554432);  // (B,S,512) bf16
  unsigned short* proj   = (unsigned short*)al(33554432);  // (B,S,512) bf16
  unsigned short* WF     = (unsigned short*)al(1048576);   // 1024x512
  unsigned short* WB     = (unsigned short*)al(1048576);
  unsigned short* WD     = (unsigned short*)al(4456448);   // 2048x1088
  unsigned short* WC     = (unsigned short*)al(1048576);   // 512x1024
  unsigned short* WS     = (unsigned short*)al(524288);    // 512x512
  float* bFr = (float*)al(4096);
  float* bBr = (float*)al(4096);
  float* bDr = (float*)al(8192);
  (void)ws_size; (void)in_sizes; (void)n_in; (void)out_size;

  float* out_main = (float*)d_out;
  float* out_attn = out_main + (size_t)B*T*DOF;

  const dim3 blk(256);
  k_build_encw  <<<4096,  blk, 0, stream>>>(eWihF, eWhhF, eWihB, eWhhB, WF, WB);
  k_build_decw  <<<8704,  blk, 0, stream>>>(dWih, dWhh, WD);
  k_build_plainw<<<3072,  blk, 0, stream>>>(Wctx, Wsrc, WC, WS);
  k_build_bias  <<<16,    blk, 0, stream>>>(ebF, ebB, dB, bFr, bBr, bDr);
  k_embed       <<<32768, blk, 0, stream>>>(in_seq, embedding, emb);
  k_win         <<<8192,  blk, 0, stream>>>(tgt, win);
  hipMemsetAsync(stateBase, 0, stateBytes, stream);

  // persistent encoder: 256 steps internally
  k_encoder<<<256, blk, 0, stream>>>(emb, WF, WB, bFr, bBr, hEnc, encOut, cnts + 96);

  // proj = enc_out @ W_src^T  (M=32768, N=512, K=512) — fully parallel
  k_gemm_plain<<<8192, blk, 0, stream>>>(encOut, 512, 512, WS, 512, 16, proj, 512);

  // persistent decoder: 256 steps internally
  k_decoder<<<256, blk, 0, stream>>>(win, WD, bDr, WC, proj, encOut, in_seq,
                                     Wout, bout, hdec, feed, ctxb,
                                     out_main, out_attn, cnts);
}

// Round 4
// 11191.864 us; speedup vs baseline: 7.3500x; 1.2627x over previous
//
#include <hip/hip_runtime.h>
#include <stdint.h>

// Problem constants (match reference)
#define B 128
#define S 256
#define T 256
#define EMBED 256
#define ENC 256
#define DEC 512
#define DOF 4

typedef __attribute__((ext_vector_type(8))) short bf16x8;   // 8 bf16 = 4 VGPRs (MFMA A/B frag)
typedef __attribute__((ext_vector_type(4))) float f32x4;    // MFMA C/D frag

static __device__ __forceinline__ float bf2f(unsigned short u){
  union{uint32_t u;float f;}c; c.u = ((uint32_t)u)<<16; return c.f;
}
static __device__ __forceinline__ unsigned short f2bf(float f){
  union{float f;uint32_t u;}c; c.f=f; uint32_t u=c.u;
  u += 0x7fffu + ((u>>16)&1u);  // round-to-nearest-even
  return (unsigned short)(u>>16);
}
static __device__ __forceinline__ void unp2(uint32_t w, float&a, float&b){
  union{uint32_t u;float f;}c1,c2; c1.u = w<<16; c2.u = w & 0xffff0000u; a=c1.f; b=c2.f;
}
static __device__ __forceinline__ float sigm(float x){ return 1.0f/(1.0f+__expf(-x)); }

// ---------------------------------------------------------------------------
// Coherent (agent-scope, cache-bypassing) accessors for cross-block state.
// Read-only data (weights, encOut, win, emb) uses NORMAL cached loads.
// ---------------------------------------------------------------------------
static __device__ __forceinline__ unsigned long long ldc8(const void* p){
  return __hip_atomic_load((unsigned long long*)p, __ATOMIC_RELAXED, __HIP_MEMORY_SCOPE_AGENT);
}
static __device__ __forceinline__ void stc8(void* p, unsigned long long v){
  __hip_atomic_store((unsigned long long*)p, v, __ATOMIC_RELAXED, __HIP_MEMORY_SCOPE_AGENT);
}
static __device__ __forceinline__ void stc4(void* p, unsigned v){
  __hip_atomic_store((unsigned*)p, v, __ATOMIC_RELAXED, __HIP_MEMORY_SCOPE_AGENT);
}
static __device__ __forceinline__ void stc4f(float* p, float v){
  __hip_atomic_store((unsigned*)p, __float_as_uint(v), __ATOMIC_RELAXED, __HIP_MEMORY_SCOPE_AGENT);
}
static __device__ __forceinline__ float ldc4f(const float* p){
  return __uint_as_float(__hip_atomic_load((const unsigned*)p, __ATOMIC_RELAXED, __HIP_MEMORY_SCOPE_AGENT));
}
union F16x8 { unsigned long long q[2]; bf16x8 v; unsigned short s[8]; };
union Ubf   { bf16x8 v; uint32_t u[4]; unsigned short s[8]; };
static __device__ __forceinline__ bf16x8 ldfrag_c(const unsigned short* p){
  F16x8 u; u.q[0] = ldc8(p); u.q[1] = ldc8(p + 4); return u.v;
}
static __device__ __forceinline__ unsigned long long pack4bf(float a,float b,float c,float d){
  return (unsigned long long)f2bf(a) | ((unsigned long long)f2bf(b)<<16)
       | ((unsigned long long)f2bf(c)<<32) | ((unsigned long long)f2bf(d)<<48);
}

// ---------------------------------------------------------------------------
// Spread-counter device barriers: 16 cache lines per barrier set; arrivals
// fetch_add their line; one wave polls all 16 lines (__all across 64 lanes).
// ---------------------------------------------------------------------------
#define CLINE 32   // u32 per counter line (128 B)
#define A_OFF 0
#define Q_OFF 16
#define C_OFF 32
#define F_OFF 48
#define PAIR_OFF 64
#define ENC_OFF 192
static __device__ __forceinline__ unsigned* cl(unsigned* c, int line){ return c + (size_t)line*CLINE; }

static __device__ __forceinline__ void bar_arr(unsigned* line){
  __builtin_amdgcn_s_waitcnt(0);     // drain this wave's coherent stores
  __syncthreads();                   // all waves drained
  if (threadIdx.x == 0)
    __hip_atomic_fetch_add(line, 1u, __ATOMIC_RELAXED, __HIP_MEMORY_SCOPE_AGENT);
}
static __device__ __forceinline__ void barw(unsigned* set16, unsigned target){
  if (threadIdx.x < 64){
    unsigned* p = set16 + (size_t)(threadIdx.x & 15)*CLINE;
    while (!__all((int)(__hip_atomic_load(p, __ATOMIC_RELAXED, __HIP_MEMORY_SCOPE_AGENT) >= target)))
      __builtin_amdgcn_s_sleep(1);
  }
  __syncthreads();
  asm volatile("" ::: "memory");
}
static __device__ __forceinline__ void pair_sync(unsigned* line, unsigned target){
  __builtin_amdgcn_s_waitcnt(0);
  __syncthreads();
  if (threadIdx.x == 0){
    __hip_atomic_fetch_add(line, 1u, __ATOMIC_RELAXED, __HIP_MEMORY_SCOPE_AGENT);
    while (__hip_atomic_load(line, __ATOMIC_RELAXED, __HIP_MEMORY_SCOPE_AGENT) < target)
      __builtin_amdgcn_s_sleep(1);
  }
  __syncthreads();
  asm volatile("" ::: "memory");
}

// swizzled LDS index (in shorts) for encS: row s (0..255), 16B-chunk c (0..31)
static __device__ __forceinline__ int enc_idx(int s, int c){
  return s*256 + (((c & 24) | ((c ^ s) & 7)) << 3);
}

// ---------------------------------------------------------------------------
// Persistent bi-LSTM encoder. Grid 256 = dir(2) x mg(2) x ng(64).
// Weight slice (16x512) in LDS all 256 steps; c in registers. Spread-counter
// per-direction barrier; emb A-frags prefetched before the barrier wait.
// ---------------------------------------------------------------------------
__global__ __launch_bounds__(256,1) void k_encoder(
  const unsigned short* __restrict__ emb,   // (S,B,256)
  const unsigned short* __restrict__ WF, const unsigned short* __restrict__ WB,
  const float* __restrict__ bF, const float* __restrict__ bB,
  unsigned short* __restrict__ hEnc,        // [dir][2][B][256]
  unsigned short* __restrict__ encOut,      // [B][S][512]
  unsigned* __restrict__ cntBase)           // 2 sets of 16 lines
{
  __shared__ __align__(16) unsigned short Ws[16*520];
  __shared__ __align__(16) float Gs[64*17];
  __shared__ float bsh[16];
  const int bid = blockIdx.x;
  const int dir = bid >> 7;
  const int mg  = (bid >> 6) & 1;
  const int ng  = bid & 63;
  const int tid = threadIdx.x;
  const int lane = tid & 63, w = tid >> 6;
  const int l16 = lane & 15, qd = lane >> 4;
  const int m_base = mg * 64;
  unsigned* mycnt = cntBase + (size_t)dir*16*CLINE;
  unsigned* myline = cl(mycnt, bid & 15);

  const unsigned short* Wg = (dir ? WB : WF) + (size_t)ng*16*512;
  for (int i = tid; i < 16*64; i += 256){
    const int r = i >> 6, s = i & 63;
    *(uint4*)&Ws[r*520 + s*8] = *(const uint4*)&Wg[r*512 + s*8];
  }
  if (tid < 16) bsh[tid] = (dir ? bB : bF)[ng*16 + tid];
  float c[4] = {0.f,0.f,0.f,0.f};
  __syncthreads();

  for (int t = 0; t < S; ++t){
    const int tt = dir ? (S-1-t) : t;
    const unsigned short* Ae = emb + ((size_t)tt*B + m_base + w*16 + l16)*256 + qd*8;
    bf16x8 av[8];
#pragma unroll
    for (int ks = 0; ks < 8; ++ks) av[ks] = *(const bf16x8*)(Ae + ks*32);   // prefetch (cached)
    if (t) barw(mycnt, (unsigned)(8u*(unsigned)t));
    const unsigned short* Ah = hEnc + (((size_t)dir*2 + (size_t)(t&1))*B + m_base + w*16 + l16)*256 + qd*8;
    bf16x8 hf[8];
#pragma unroll
    for (int ks = 0; ks < 8; ++ks) hf[ks] = ldfrag_c(Ah + ks*32);
    f32x4 acc = (f32x4){0.f,0.f,0.f,0.f};
#pragma unroll
    for (int ks = 0; ks < 8; ++ks){
      bf16x8 bb = *(const bf16x8*)&Ws[l16*520 + ks*32 + qd*8];
      acc = __builtin_amdgcn_mfma_f32_16x16x32_bf16(av[ks], bb, acc, 0, 0, 0);
    }
#pragma unroll
    for (int ks = 0; ks < 8; ++ks){
      bf16x8 bb = *(const bf16x8*)&Ws[l16*520 + 256 + ks*32 + qd*8];
      acc = __builtin_amdgcn_mfma_f32_16x16x32_bf16(hf[ks], bb, acc, 0, 0, 0);
    }
    __syncthreads();
#pragma unroll
    for (int r = 0; r < 4; ++r)
      Gs[(w*16 + qd*4 + r)*17 + l16] = acc[r];
    __syncthreads();
    if (tid < 64){
      const int bl = tid;
      float hv[4];
#pragma unroll
      for (int u = 0; u < 4; ++u){
        const float gi = Gs[bl*17 + u*4 + 0] + bsh[u*4 + 0];
        const float gf = Gs[bl*17 + u*4 + 1] + bsh[u*4 + 1];
        const float gg = Gs[bl*17 + u*4 + 2] + bsh[u*4 + 2];
        const float go = Gs[bl*17 + u*4 + 3] + bsh[u*4 + 3];
        const float cn = sigm(gf)*c[u] + sigm(gi)*tanhf(gg);
        c[u] = cn;
        hv[u] = sigm(go)*tanhf(cn);
      }
      const int b2 = m_base + bl;
      const unsigned long long hq = pack4bf(hv[0],hv[1],hv[2],hv[3]);
      stc8(&hEnc[(((size_t)dir*2 + (size_t)((t+1)&1))*B + b2)*256 + ng*4], hq);
      *(unsigned long long*)&encOut[((size_t)b2*S + tt)*512 + dir*256 + ng*4] = hq;
    }
    bar_arr(myline);
  }
}

// ---------------------------------------------------------------------------
// Persistent decoder. Grid 256; block i owns (batch b=i>>1, e-half eh=i&1),
// holds encOut[b, :, eh*256..+256) swizzled in LDS (128 KB) for all 256 steps.
// Roles: all blocks gates tile (mg=i&1, ng=(i>>1)&127) + attention;
//        bid%4==2 -> q GEMM; bid%4==3 -> feed GEMM; odd bid -> outproj.
// Per step: gates -> barA -> q -> barQ -> scores(pair-combined)+softmax+ctx
//           -> barC -> feed -> barF.
// ---------------------------------------------------------------------------
__global__ __launch_bounds__(256,1) void k_decoder(
  const unsigned short* __restrict__ win,    // (T,B,64)
  const unsigned short* __restrict__ WDx,    // swizzled gates weights
  const float* __restrict__ bD,              // 2048 reordered
  const unsigned short* __restrict__ WCx,    // swizzled W_ctx
  const unsigned short* __restrict__ WSTx,   // swizzled W_src (q = h @ W_src)
  const unsigned short* __restrict__ encOut, // (B,S,512)
  const int* __restrict__ in_seq,
  const float* __restrict__ Wout, const float* __restrict__ bout,
  unsigned short* __restrict__ hdec,         // [2][B][512]
  unsigned short* __restrict__ feed,         // [B][512]
  unsigned short* __restrict__ ctxb,         // [B][512]
  unsigned short* __restrict__ q,            // [B][512]
  float* __restrict__ scp,                   // [B][2][256] partial scores
  float* __restrict__ out_main, float* __restrict__ out_attn,
  unsigned* __restrict__ cnts)
{
  __shared__ __align__(16) unsigned short encS[65536];  // 128 KB resident tile
  __shared__ __align__(16) float scrf[1600];            // Gs / qs / aw / red / ctx-partials
  __shared__ float bsh[16];
  const int bid = blockIdx.x;
  const int b  = bid >> 1, eh = bid & 1;
  const int mg = bid & 1, ng = (bid >> 1) & 127;
  const int tid = threadIdx.x;
  const int lane = tid & 63, w = tid >> 6;
  const int l16 = lane & 15, qd = lane >> 4;
  const int m_base = mg*64;

  // ---- init: bias, mask, resident encOut tile ----
  if (tid < 16) bsh[tid] = bD[ng*16 + tid];
  const int mymask = (in_seq[b*S + tid] == 0);
  for (int i = 0; i < 32; ++i){
    const int s = i*8 + (tid>>5), cc = tid & 31;
    const uint4 v = *(const uint4*)&encOut[((size_t)b*S + s)*512 + eh*256 + cc*8];
    *(uint4*)&encS[enc_idx(s, cc)] = v;
  }
  float c[4] = {0.f,0.f,0.f,0.f};
  __syncthreads();

  for (int t = 0; t < T; ++t){
    if (t) barw(cl(cnts, F_OFF), (unsigned)(4u*(unsigned)t));   // feed_{t-1} ready
    // ---------------- phase A: gates + LSTM update ----------------
    const int row = m_base + w*16 + l16;
    const unsigned short* Aw = win  + ((size_t)t*B + row)*64 + qd*8;
    const unsigned short* Af = feed + (size_t)row*512 + qd*8;
    const unsigned short* Ah = hdec + ((size_t)(t&1)*B + row)*512 + qd*8;
    const unsigned short* Bp = WDx + (size_t)ng*34*512 + (size_t)lane*8;
    f32x4 acc = (f32x4){0.f,0.f,0.f,0.f};
    {
      bf16x8 bv[17], av[17];
#pragma unroll
      for (int ks = 0; ks < 17; ++ks) bv[ks] = *(const bf16x8*)(Bp + (size_t)ks*512);
      av[0] = *(const bf16x8*)(Aw);
      av[1] = *(const bf16x8*)(Aw + 32);
#pragma unroll
      for (int i = 0; i < 15; ++i) av[2+i] = ldfrag_c(Af + i*32);
#pragma unroll
      for (int ks = 0; ks < 17; ++ks)
        acc = __builtin_amdgcn_mfma_f32_16x16x32_bf16(av[ks], bv[ks], acc, 0, 0, 0);
    }
    {
      bf16x8 bv[17], av[17];
#pragma unroll
      for (int ks = 0; ks < 17; ++ks) bv[ks] = *(const bf16x8*)(Bp + (size_t)(17+ks)*512);
      av[0] = ldfrag_c(Af + 15*32);
#pragma unroll
      for (int i = 0; i < 16; ++i) av[1+i] = ldfrag_c(Ah + i*32);
#pragma unroll
      for (int ks = 0; ks < 17; ++ks)
        acc = __builtin_amdgcn_mfma_f32_16x16x32_bf16(av[ks], bv[ks], acc, 0, 0, 0);
    }
    __syncthreads();
#pragma unroll
    for (int r = 0; r < 4; ++r)
      scrf[(w*16 + qd*4 + r)*17 + l16] = acc[r];
    __syncthreads();
    if (tid < 64){
      float hv[4];
#pragma unroll
      for (int u = 0; u < 4; ++u){
        const float gi = scrf[tid*17 + u*4 + 0] + bsh[u*4 + 0];
        const float gf = scrf[tid*17 + u*4 + 1] + bsh[u*4 + 1];
        const float gg = scrf[tid*17 + u*4 + 2] + bsh[u*4 + 2];
        const float go = scrf[tid*17 + u*4 + 3] + bsh[u*4 + 3];
        const float cn = sigm(gf)*c[u] + sigm(gi)*tanhf(gg);
        c[u] = cn;
        hv[u] = sigm(go)*tanhf(cn);
      }
      stc8(&hdec[((size_t)((t+1)&1)*B + m_base + tid)*512 + ng*4],
           pack4bf(hv[0],hv[1],hv[2],hv[3]));
    }
    bar_arr(cl(cnts, A_OFF + (bid & 15)));

    // out-projection of feed_{t-1} (overlaps q phase; odd blocks, 1 batch each)
    if ((bid & 1) && t > 0){
      const int b2o = bid >> 1;
      const int d = tid >> 6, kk = lane;
      const unsigned short* fp = feed + (size_t)b2o*512 + kk*8;
      F16x8 u; u.q[0] = ldc8(fp); u.q[1] = ldc8(fp + 4);
      const float* wp = Wout + d*512 + kk*8;
      float p = 0.f;
#pragma unroll
      for (int j2 = 0; j2 < 8; ++j2) p += bf2f(u.s[j2]) * wp[j2];
#pragma unroll
      for (int off = 32; off > 0; off >>= 1) p += __shfl_down(p, off, 64);
      if (kk == 0){
        const float v = p + bout[d];
        out_main[((size_t)b2o*T + (t-1))*4 + d] = (d < 3) ? tanhf(v) : fmaxf(v, 0.f);
      }
    }

    // ---------------- phase Q: q = h_t @ W_src (64 blocks) ----------------
    if ((bid & 3) == 2){
      barw(cl(cnts, A_OFF), (unsigned)(16u*(unsigned)(t+1)));
      const int qblk = bid >> 2, qm = qblk >> 5, qn = qblk & 31;
      const int qrow = qm*64 + w*16 + l16;
      const unsigned short* Aq = hdec + ((size_t)((t+1)&1)*B + qrow)*512 + qd*8;
      const unsigned short* Bq = WSTx + (size_t)qn*16*512 + (size_t)lane*8;
      bf16x8 bv[16], av[16];
#pragma unroll
      for (int ks = 0; ks < 16; ++ks) bv[ks] = *(const bf16x8*)(Bq + (size_t)ks*512);
#pragma unroll
      for (int ks = 0; ks < 16; ++ks) av[ks] = ldfrag_c(Aq + ks*32);
      f32x4 qa = (f32x4){0.f,0.f,0.f,0.f};
#pragma unroll
      for (int ks = 0; ks < 16; ++ks)
        qa = __builtin_amdgcn_mfma_f32_16x16x32_bf16(av[ks], bv[ks], qa, 0, 0, 0);
      __syncthreads();
#pragma unroll
      for (int r = 0; r < 4; ++r)
        scrf[(w*16 + qd*4 + r)*17 + l16] = qa[r];
      __syncthreads();
      if (tid < 64){
        const int qb = qm*64 + tid;
#pragma unroll
        for (int u = 0; u < 4; ++u)
          stc8(&q[(size_t)qb*512 + qn*16 + u*4],
               pack4bf(scrf[tid*17+u*4+0], scrf[tid*17+u*4+1],
                       scrf[tid*17+u*4+2], scrf[tid*17+u*4+3]));
      }
      bar_arr(cl(cnts, Q_OFF + ((bid >> 2) & 15)));
    }

    // ---------------- attention (all blocks; e-half of batch b) ----------------
    barw(cl(cnts, Q_OFF), (unsigned)(4u*(unsigned)(t+1)));
    if (tid < 64){
      F16x8 uq; uq.q[0] = ldc8(q + (size_t)b*512 + eh*256 + tid*4);
      scrf[tid*4+0] = bf2f(uq.s[0]); scrf[tid*4+1] = bf2f(uq.s[1]);
      scrf[tid*4+2] = bf2f(uq.s[2]); scrf[tid*4+3] = bf2f(uq.s[3]);
    }
    __syncthreads();
    float sc = 0.f;
#pragma unroll 8
    for (int cix = 0; cix < 32; ++cix){
      Ubf u8; u8.v = *(const bf16x8*)&encS[enc_idx(tid, cix)];
      float f0,f1,f2,f3,f4,f5,f6,f7;
      unp2(u8.u[0],f0,f1); unp2(u8.u[1],f2,f3); unp2(u8.u[2],f4,f5); unp2(u8.u[3],f6,f7);
      const float* qp = &scrf[cix*8];
      sc += f0*qp[0] + f1*qp[1] + f2*qp[2] + f3*qp[3]
          + f4*qp[4] + f5*qp[5] + f6*qp[6] + f7*qp[7];
    }
    stc4f(&scp[((size_t)b*2 + eh)*256 + tid], sc);
    pair_sync(cl(cnts, PAIR_OFF + b), (unsigned)(2u*(unsigned)(t+1)));
    float tot = sc + ldc4f(&scp[((size_t)b*2 + (1-eh))*256 + tid]);
    if (mymask) tot = -1e30f;
    // softmax over 256 s
    float mx = tot;
#pragma unroll
    for (int off = 32; off > 0; off >>= 1) mx = fmaxf(mx, __shfl_xor(mx, off, 64));
    if (lane == 0) scrf[512 + w] = mx;
    __syncthreads();
    mx = fmaxf(fmaxf(scrf[512], scrf[513]), fmaxf(scrf[514], scrf[515]));
    const float e = __expf(tot - mx);
    float l = e;
#pragma unroll
    for (int off = 32; off > 0; off >>= 1) l += __shfl_xor(l, off, 64);
    if (lane == 0) scrf[516 + w] = l;
    __syncthreads();
    l = scrf[516] + scrf[517] + scrf[518] + scrf[519];
    const float aw = e / l;
    scrf[256 + tid] = aw;
    if (eh == 0) __builtin_nontemporal_store(aw, &out_attn[((size_t)b*T + t)*S + tid]);
    __syncthreads();
    // ctx e-half: wave w covers 64 s rows (2 per iter), lane owns 8-e chunk
    {
      float a[8] = {0,0,0,0,0,0,0,0};
      const int cc = lane & 31, par = lane >> 5;
      for (int i2 = 0; i2 < 32; ++i2){
        const int srow = w*64 + i2*2 + par;
        const float wgt = scrf[256 + srow];
        Ubf u8; u8.v = *(const bf16x8*)&encS[enc_idx(srow, cc)];
        float f0,f1,f2,f3,f4,f5,f6,f7;
        unp2(u8.u[0],f0,f1); unp2(u8.u[1],f2,f3); unp2(u8.u[2],f4,f5); unp2(u8.u[3],f6,f7);
        a[0]+=wgt*f0; a[1]+=wgt*f1; a[2]+=wgt*f2; a[3]+=wgt*f3;
        a[4]+=wgt*f4; a[5]+=wgt*f5; a[6]+=wgt*f6; a[7]+=wgt*f7;
      }
#pragma unroll
      for (int j2 = 0; j2 < 8; ++j2) a[j2] += __shfl_xor(a[j2], 32, 64);
      if (par == 0){
#pragma unroll
        for (int j2 = 0; j2 < 8; ++j2) scrf[528 + w*256 + cc*8 + j2] = a[j2];
      }
    }
    __syncthreads();
    if (tid < 128){
      const int e2 = tid*2;
      const float s0 = scrf[528+e2]     + scrf[528+256+e2]     + scrf[528+512+e2]     + scrf[528+768+e2];
      const float s1 = scrf[528+e2+1]   + scrf[528+256+e2+1]   + scrf[528+512+e2+1]   + scrf[528+768+e2+1];
      stc4(&ctxb[(size_t)b*512 + eh*256 + e2],
           (unsigned)f2bf(s0) | ((unsigned)f2bf(s1) << 16));
    }
    bar_arr(cl(cnts, C_OFF + (bid & 15)));

    // ---------------- phase F: feed = tanh([h|ctx] @ W_ctx^T) (64 blocks) ----
    if ((bid & 3) == 3){
      barw(cl(cnts, C_OFF), (unsigned)(16u*(unsigned)(t+1)));
      const int fblk = bid >> 2, fm = fblk >> 5, fn = fblk & 31;
      const int frow = fm*64 + w*16 + l16;
      const unsigned short* Fh = hdec + ((size_t)((t+1)&1)*B + frow)*512 + qd*8;
      const unsigned short* Fc = ctxb + (size_t)frow*512 + qd*8;
      const unsigned short* Bf = WCx + (size_t)fn*32*512 + (size_t)lane*8;
      f32x4 fa = (f32x4){0.f,0.f,0.f,0.f};
      {
        bf16x8 bv[16], av[16];
#pragma unroll
        for (int ks = 0; ks < 16; ++ks) bv[ks] = *(const bf16x8*)(Bf + (size_t)ks*512);
#pragma unroll
        for (int ks = 0; ks < 16; ++ks) av[ks] = ldfrag_c(Fh + ks*32);
#pragma unroll
        for (int ks = 0; ks < 16; ++ks)
          fa = __builtin_amdgcn_mfma_f32_16x16x32_bf16(av[ks], bv[ks], fa, 0, 0, 0);
      }
      {
        bf16x8 bv[16], av[16];
#pragma unroll
        for (int ks = 0; ks < 16; ++ks) bv[ks] = *(const bf16x8*)(Bf + (size_t)(16+ks)*512);
#pragma unroll
        for (int ks = 0; ks < 16; ++ks) av[ks] = ldfrag_c(Fc + ks*32);
#pragma unroll
        for (int ks = 0; ks < 16; ++ks)
          fa = __builtin_amdgcn_mfma_f32_16x16x32_bf16(av[ks], bv[ks], fa, 0, 0, 0);
      }
      __syncthreads();
#pragma unroll
      for (int r = 0; r < 4; ++r)
        scrf[(w*16 + qd*4 + r)*17 + l16] = tanhf(fa[r]);
      __syncthreads();
      if (tid < 64){
        const int fb = fm*64 + tid;
#pragma unroll
        for (int u = 0; u < 4; ++u)
          stc8(&feed[(size_t)fb*512 + fn*16 + u*4],
               pack4bf(scrf[tid*17+u*4+0], scrf[tid*17+u*4+1],
                       scrf[tid*17+u*4+2], scrf[tid*17+u*4+3]));
      }
      bar_arr(cl(cnts, F_OFF + ((bid >> 2) & 15)));
    }
  }
  // final out-projection (feed_255)
  if (bid & 1){
    barw(cl(cnts, F_OFF), (unsigned)(4u*256u));
    const int b2o = bid >> 1;
    const int d = tid >> 6, kk = lane;
    const unsigned short* fp = feed + (size_t)b2o*512 + kk*8;
    F16x8 u; u.q[0] = ldc8(fp); u.q[1] = ldc8(fp + 4);
    const float* wp = Wout + d*512 + kk*8;
    float p = 0.f;
#pragma unroll
    for (int j2 = 0; j2 < 8; ++j2) p += bf2f(u.s[j2]) * wp[j2];
#pragma unroll
    for (int off = 32; off > 0; off >>= 1) p += __shfl_down(p, off, 64);
    if (kk == 0){
      const float v = p + bout[d];
      out_main[((size_t)b2o*T + 255)*4 + d] = (d < 3) ? tanhf(v) : fmaxf(v, 0.f);
    }
  }
}

// ---------------- setup / builder kernels ----------------
__global__ __launch_bounds__(256) void k_build_encw(
  const float* __restrict__ WihF, const float* __restrict__ WhhF,
  const float* __restrict__ WihB, const float* __restrict__ WhhB,
  unsigned short* WF, unsigned short* WB)
{
  const int idx = blockIdx.x*256 + threadIdx.x;     // 2*1024*512
  const int dir = idx >> 19;
  const int i2 = idx & 524287;
  const int row = i2 >> 9, col = i2 & 511;
  const int j = row >> 2, g = row & 3;
  const int orig = g*256 + j;
  const float* Wih = dir ? WihB : WihF;
  const float* Whh = dir ? WhhB : WhhF;
  const float v = (col < 256) ? Wih[orig*256 + col] : Whh[orig*256 + (col-256)];
  (dir ? WB : WF)[i2] = f2bf(v);
}

// gates weights: reorder rows (j*4+g), pad cols to 1088, swizzle to frag order
__global__ __launch_bounds__(256) void k_build_decw(
  const float* __restrict__ Wih, const float* __restrict__ Whh, unsigned short* WDx)
{
  const int idx = blockIdx.x*256 + threadIdx.x;
  if (idx >= 2048*1088) return;
  const int row = idx / 1088, col = idx - row*1088;
  const int j = row >> 2, g = row & 3;
  const int orig = g*512 + j;
  float v;
  if (col < 16)        v = Wih[orig*528 + col];          // w_t part
  else if (col < 64)   v = 0.f;                          // pad
  else if (col < 576)  v = Wih[orig*528 + (col - 48)];   // feed part
  else                 v = Whh[orig*512 + (col - 576)];  // h part
  const int ng = row >> 4, l16 = row & 15;
  const int ks = col >> 5, qdd = (col >> 3) & 3, jj = col & 7;
  WDx[(((size_t)ng*34 + ks)*64 + qdd*16 + l16)*8 + jj] = f2bf(v);
}

__global__ __launch_bounds__(256) void k_build_wcx(
  const float* __restrict__ Wctx, unsigned short* WCx)
{
  const int idx = blockIdx.x*256 + threadIdx.x;     // 512*1024
  const int n = idx >> 10, k = idx & 1023;
  const int fn = n >> 4, l16 = n & 15;
  const int ks = k >> 5, qdd = (k >> 3) & 3, jj = k & 7;
  WCx[(((size_t)fn*32 + ks)*64 + qdd*16 + l16)*8 + jj] = f2bf(Wctx[(size_t)n*1024 + k]);
}

__global__ __launch_bounds__(256) void k_build_wstx(
  const float* __restrict__ Wsrc, unsigned short* WSTx)
{
  const int idx = blockIdx.x*256 + threadIdx.x;     // 512*512, n=e, k=d
  const int e = idx >> 9, d = idx & 511;
  const int qn = e >> 4, l16 = e & 15;
  const int ks = d >> 5, qdd = (d >> 3) & 3, jj = d & 7;
  WSTx[(((size_t)qn*16 + ks)*64 + qdd*16 + l16)*8 + jj] = f2bf(Wsrc[(size_t)d*512 + e]);
}

__global__ __launch_bounds__(256) void k_build_bias(
  const float* __restrict__ ebF, const float* __restrict__ ebB,
  const float* __restrict__ dB, float* bF, float* bB, float* bD)
{
  const int idx = blockIdx.x*256 + threadIdx.x;     // 4096
  if (idx < 1024) bF[idx] = ebF[(idx&3)*256 + (idx>>2)];
  else if (idx < 2048){ const int i = idx-1024; bB[i] = ebB[(i&3)*256 + (i>>2)]; }
  else { const int i = idx-2048; bD[i] = dB[(i&3)*512 + (i>>2)]; }
}

__global__ __launch_bounds__(256) void k_embed(
  const int* __restrict__ in_seq, const float* __restrict__ table, unsigned short* emb)
{
  const int idx = blockIdx.x*256 + threadIdx.x;     // S*B*256, layout (S,B,E)
  const int e = idx & 255, b = (idx >> 8) & 127, s = idx >> 15;
  const int tok = in_seq[b*S + s];
  emb[idx] = f2bf(table[(size_t)tok*256 + e]);
}

__global__ __launch_bounds__(256) void k_win(
  const float* __restrict__ tgt, unsigned short* win)
{
  const int idx = blockIdx.x*256 + threadIdx.x;     // T*B*64, layout (T,B,64)
  const int c = idx & 63, b = (idx >> 6) & 127, t = idx >> 13;
  float v = 0.f;
  if (c < 16){
    const int k = c >> 2, jj = c & 3;
    const int ts = t + k - 4;
    if (ts >= 0) v = tgt[((size_t)b*T + ts)*4 + jj];
  }
  win[idx] = f2bf(v);
}

// ---------------------------------------------------------------------------
extern "C" void kernel_launch(void* const* d_in, const int* in_sizes, int n_in,
                              void* d_out, int out_size, void* d_ws, size_t ws_size,
                              hipStream_t stream)
{
  const int*   in_seq    = (const int*)d_in[0];
  const float* tgt       = (const float*)d_in[1];
  // d_in[2] = lengths (unused by reference)
  const float* embedding = (const float*)d_in[3];
  const float* eWihF = (const float*)d_in[4];
  const float* eWhhF = (const float*)d_in[5];
  const float* ebF   = (const float*)d_in[6];
  const float* eWihB = (const float*)d_in[7];
  const float* eWhhB = (const float*)d_in[8];
  const float* ebB   = (const float*)d_in[9];
  const float* dWih  = (const float*)d_in[10];
  const float* dWhh  = (const float*)d_in[11];
  const float* dB    = (const float*)d_in[12];
  const float* Wsrc  = (const float*)d_in[13];
  const float* Wctx  = (const float*)d_in[14];
  const float* Wout  = (const float*)d_in[15];
  const float* bout  = (const float*)d_in[16];

  char* ws = (char*)d_ws;
  size_t off = 0;
  auto al = [&](size_t bytes)->char*{
    char* p = ws + off; off += (bytes + 255) & ~(size_t)255; return p; };

  // --- state region (zeroed every launch with one memset) ---
  char* stateBase = ws;
  unsigned short* hEnc = (unsigned short*)al(262144);  // [2][2][128][256]
  unsigned short* hdec = (unsigned short*)al(262144);  // [2][128][512]
  unsigned short* feed = (unsigned short*)al(131072);  // [128][512]
  unsigned short* ctxb = (unsigned short*)al(131072);  // [128][512]
  unsigned*       cnts = (unsigned*)al(28672);         // 224 counter lines
  const size_t stateBytes = off;

  // --- persistent-per-launch scratch (fully rewritten each launch) ---
  unsigned short* emb    = (unsigned short*)al(16777216);  // (S,B,256) bf16
  unsigned short* win    = (unsigned short*)al(4194304);   // (T,B,64) bf16
  unsigned short* encOut = (unsigned short*)al(33554432);  // (B,S,512) bf16
  unsigned short* WF     = (unsigned short*)al(1048576);   // 1024x512
  unsigned short* WB     = (unsigned short*)al(1048576);
  unsigned short* WDx    = (unsigned short*)al(4456448);   // swizzled 2048x1088
  unsigned short* WCx    = (unsigned short*)al(1048576);   // swizzled 512x1024
  unsigned short* WSTx   = (unsigned short*)al(524288);    // swizzled 512x512
  unsigned short* qbuf   = (unsigned short*)al(131072);    // [128][512]
  float*          scp    = (float*)al(262144);             // [128][2][256]
  float* bFr = (float*)al(4096);
  float* bBr = (float*)al(4096);
  float* bDr = (float*)al(8192);
  (void)ws_size; (void)in_sizes; (void)n_in; (void)out_size;

  float* out_main = (float*)d_out;
  float* out_attn = out_main + (size_t)B*T*DOF;

  const dim3 blk(256);
  k_build_encw <<<4096,  blk, 0, stream>>>(eWihF, eWhhF, eWihB, eWhhB, WF, WB);
  k_build_decw <<<8704,  blk, 0, stream>>>(dWih, dWhh, WDx);
  k_build_wcx  <<<2048,  blk, 0, stream>>>(Wctx, WCx);
  k_build_wstx <<<1024,  blk, 0, stream>>>(Wsrc, WSTx);
  k_build_bias <<<16,    blk, 0, stream>>>(ebF, ebB, dB, bFr, bBr, bDr);
  k_embed      <<<32768, blk, 0, stream>>>(in_seq, embedding, emb);
  k_win        <<<8192,  blk, 0, stream>>>(tgt, win);
  hipMemsetAsync(stateBase, 0, stateBytes, stream);

  // persistent encoder: 256 steps internally
  k_encoder<<<256, blk, 0, stream>>>(emb, WF, WB, bFr, bBr, hEnc, encOut,
                                     cnts + (size_t)ENC_OFF*CLINE);

  // persistent decoder: 256 steps internally (encOut LDS-resident, no proj)
  k_decoder<<<256, blk, 0, stream>>>(win, WDx, bDr, WCx, WSTx, encOut, in_seq,
                                     Wout, bout, hdec, feed, ctxb, qbuf, scp,
                                     out_main, out_attn, cnts);
}